// Round 4
// baseline (668.318 us; speedup 1.0000x reference)
//
#include <hip/hip_runtime.h>
#include <hip/hip_bf16.h>
#include <math.h>

// Problem constants (B=1, S=2048, D=1024, E=8, K=2, FF=4096)
#define T_      2048
#define D_      1024
#define E_      8
#define FF_     4096

typedef __attribute__((ext_vector_type(8))) short  bf16x8;   // MFMA A/B frag
typedef __attribute__((ext_vector_type(4))) float  f32x4;    // MFMA C/D frag
typedef __attribute__((ext_vector_type(8))) float  f32x8;
typedef __attribute__((ext_vector_type(8))) __bf16 b16x8;
typedef __attribute__((ext_vector_type(4))) __bf16 b16x4;

// async global->LDS 16B copy. LDS dest is WAVE-UNIFORM base; HW adds lane*16.
static __device__ inline void async_copy16(const void* g, void* l) {
    __builtin_amdgcn_global_load_lds(
        (const __attribute__((address_space(1))) unsigned int*)g,
        (__attribute__((address_space(3))) unsigned int*)l, 16, 0, 0);
}

// 8x fp32 -> packed bf16x8 (RNE)
static __device__ inline bf16x8 cvt8(float4 a, float4 b) {
    f32x8 x;
    x[0] = a.x; x[1] = a.y; x[2] = a.z; x[3] = a.w;
    x[4] = b.x; x[5] = b.y; x[6] = b.z; x[7] = b.w;
    b16x8 c = __builtin_convertvector(x, b16x8);
    return *(bf16x8*)&c;
}

// ---------------------------------------------------------------------------
// Router (fp32): logits, top-2 + renorm, per-expert (token, weight) lists.
// Also converts h -> bf16 (hbf). Softmax denom cancels in top-2 renorm.
// ---------------------------------------------------------------------------
__global__ __launch_bounds__(256) void router_kernel(
    const float* __restrict__ h, const float* __restrict__ gw,
    __bf16* __restrict__ hbf, float* __restrict__ logits,
    int* __restrict__ counts, int* __restrict__ lists, float* __restrict__ wlist)
{
    int t = blockIdx.x * 4 + (threadIdx.x >> 6);
    int lane = threadIdx.x & 63;
    const float4* hrow = (const float4*)(h + (size_t)t * D_);   // 256 float4
    const float4* gw4  = (const float4*)gw;                     // [E][256]
    float part[E_];
#pragma unroll
    for (int e = 0; e < E_; ++e) part[e] = 0.f;
#pragma unroll 4
    for (int i = lane; i < 256; i += 64) {
        float4 v = hrow[i];
        f32x4 vv; vv[0] = v.x; vv[1] = v.y; vv[2] = v.z; vv[3] = v.w;
        b16x4 bv = __builtin_convertvector(vv, b16x4);
        *(b16x4*)(hbf + (size_t)t * D_ + i * 4) = bv;
#pragma unroll
        for (int e = 0; e < E_; ++e) {
            float4 g = gw4[e * 256 + i];
            part[e] += v.x * g.x + v.y * g.y + v.z * g.z + v.w * g.w;
        }
    }
#pragma unroll
    for (int e = 0; e < E_; ++e) {
        float v = part[e];
#pragma unroll
        for (int off = 32; off > 0; off >>= 1) v += __shfl_down(v, off, 64);
        part[e] = v;
    }
    if (lane == 0) {
        float* lo = logits + (size_t)t * E_;
#pragma unroll
        for (int e = 0; e < E_; ++e) lo[e] = part[e];
        int i0 = 0;
#pragma unroll
        for (int e = 1; e < E_; ++e) if (part[e] > part[i0]) i0 = e;
        int i1 = (i0 == 0) ? 1 : 0;
#pragma unroll
        for (int e = 0; e < E_; ++e)
            if (e != i0 && part[e] > part[i1]) i1 = e;
        float w1v = expf(part[i1] - part[i0]);
        float s = 1.0f + w1v;
        int p0 = atomicAdd(&counts[i0], 1);
        lists[i0 * T_ + p0] = t; wlist[i0 * T_ + p0] = 1.0f / s;
        int p1 = atomicAdd(&counts[i1], 1);
        lists[i1 * T_ + p1] = t; wlist[i1 * T_ + p1] = w1v / s;
    }
}

// Exclusive prefix of counts -> offs (8 values; trivial)
__global__ void prefix_kernel(const int* __restrict__ counts, int* __restrict__ offs) {
    if (threadIdx.x == 0) {
        int s = 0;
#pragma unroll
        for (int e = 0; e < E_; ++e) { offs[e] = s; s += counts[e]; }
    }
}

// ---------------------------------------------------------------------------
// K1: inter[row][ff] = silu(h@w1^T) * (h@w3^T), bf16, compact rows.
// BM=64, BN=256, BK=32; 8 waves; wave owns 64tok x 32ff of BOTH mats
// (16 MFMA : 8 ds_read_b128 per step).
// Staging (fused fp32->bf16, NO separate cvt pass):
//   A (hbf, bf16): 4 x global_load_lds segs, pre-swizzled source (r3-verified).
//   B (w1/w3 fp32): reg-staged. Waves 0-3 -> w1, 4-7 -> w3; per lane 4 units
//   of {2x global_load_dwordx4 -> cvt8 -> ds_write_b128}, swizzle on WRITE
//   addr (per-lane ds_write has no linear-dest constraint). LDS image and
//   read offsets identical to round 3 (bank-conflict-free, counter=0).
// Pipeline: issue loads(t+1) BEFORE MFMA(t); sched_barrier pins the
// cvt+ds_write block after MFMA; one __syncthreads per step (writes go to
// the buffer nobody is reading). setprio(1) around MFMA cluster (T5).
// Dispatch reorder: bid = sg*256 + tile*8 + sx -> same-slice tiles
// dispatch-adjacent AND XCD-pinned (weight panel L2-resident).
// ---------------------------------------------------------------------------
__global__ __launch_bounds__(512, 4) void gemm1_kernel(
    const __bf16* __restrict__ hbf,
    const float* __restrict__ w1f, const float* __restrict__ w3f,
    const int* __restrict__ counts, const int* __restrict__ offs,
    const int* __restrict__ lists, __bf16* __restrict__ inter)
{
    int bid   = blockIdx.x;
    int sx    = bid & 7;          // XCD id (bid % 8)
    int rr    = bid >> 3;
    int tile  = rr & 31;          // adjacent bids -> adjacent tiles
    int sg    = rr >> 5;          // 0..15
    int slice = sg * 8 + sx;      // 0..127
    int nt    = slice & 15;       // ff tile of 256
    int e     = slice >> 4;
    int ne    = counts[e];
    if (tile * 64 >= ne) return;
    int gb = offs[e];

    __shared__ __bf16 sh[2][18432];   // 72 KB: [A 64x32 | B1 256x32 | B3 256x32]

    int tid = threadIdx.x, lane = tid & 63, w = tid >> 6;
    int ln = lane & 15, q = lane >> 4;
    int r4 = lane >> 2, c4 = lane & 3;

    // ---- A staging: wave w (<4) stages seg w = token rows w*16..w*16+15 ----
    const __bf16* ga = hbf;
    if (w < 4) {
        int row = w * 16 + r4;
        int idx = tile * 64 + row; if (idx >= ne) idx = ne - 1;
        int tok = lists[e * T_ + idx];
        ga = hbf + (size_t)tok * D_ + ((c4 ^ ((row >> 1) & 3)) * 8);
    }

    // ---- B reg staging: local row base + global src (linear, k chunk l&3) --
    int rowb = (w & 3) * 64 + (lane >> 2);           // 0..255 local B row
    const float* wsrc = (w < 4) ? w1f : w3f;
    const float* gB = wsrc + ((size_t)e * FF_ + nt * 256 + rowb) * D_
                           + (lane & 3) * 8;
    int bbase = (w < 4) ? 2048 : 10240;              // B1 / B3 region base
    int wswz  = ((lane & 3) ^ ((lane >> 3) & 3)) * 8; // swizzled write chunk

    // ---- frag read element offsets (identical to round 3) ----
    int cxs = (q ^ ((ln >> 1) & 3)) * 8;
    int aoff[4], boff[2];
#pragma unroll
    for (int mt = 0; mt < 4; ++mt) aoff[mt] = (mt * 16 + ln) * 32 + cxs;
#pragma unroll
    for (int nf = 0; nf < 2; ++nf)
        boff[nf] = 2048 + (w * 32 + nf * 16 + ln) * 32 + cxs;

    f32x4 up[4][2], gt[4][2];
#pragma unroll
    for (int mt = 0; mt < 4; ++mt)
#pragma unroll
        for (int nf = 0; nf < 2; ++nf) {
            up[mt][nf] = (f32x4){0.f, 0.f, 0.f, 0.f};
            gt[mt][nf] = (f32x4){0.f, 0.f, 0.f, 0.f};
        }

    // ---- prologue: stage step 0 ----
    {
        float4 rb[4][2];
#pragma unroll
        for (int u = 0; u < 4; ++u) {
            const float* p = gB + (size_t)(u * 16) * D_;
            rb[u][0] = ((const float4*)p)[0];
            rb[u][1] = ((const float4*)p)[1];
        }
        if (w < 4) async_copy16(ga, &sh[0][w * 512]);
#pragma unroll
        for (int u = 0; u < 4; ++u)
            *(bf16x8*)&sh[0][bbase + (rowb + u * 16) * 32 + wswz] =
                cvt8(rb[u][0], rb[u][1]);
    }
    __syncthreads();

    // ---- K loop: 32 steps of BK=32 ----
    for (int t = 0; t < 32; ++t) {
        int p = t & 1;
        float4 nb[4][2];
        if (t + 1 < 32) {
#pragma unroll
            for (int u = 0; u < 4; ++u) {
                const float* pp = gB + (size_t)(u * 16) * D_ + (t + 1) * 32;
                nb[u][0] = ((const float4*)pp)[0];
                nb[u][1] = ((const float4*)pp)[1];
            }
            if (w < 4) async_copy16(ga + (t + 1) * 32, &sh[1 - p][w * 512]);
        }
        const __bf16* S = sh[p];
        bf16x8 b1v[2], b3v[2];
#pragma unroll
        for (int nf = 0; nf < 2; ++nf) {
            b1v[nf] = *(const bf16x8*)(S + boff[nf]);
            b3v[nf] = *(const bf16x8*)(S + boff[nf] + 8192);
        }
        __builtin_amdgcn_s_setprio(1);
#pragma unroll
        for (int mt = 0; mt < 4; ++mt) {
            bf16x8 a = *(const bf16x8*)(S + aoff[mt]);
#pragma unroll
            for (int nf = 0; nf < 2; ++nf) {
                up[mt][nf] = __builtin_amdgcn_mfma_f32_16x16x32_bf16(a, b1v[nf], up[mt][nf], 0, 0, 0);
                gt[mt][nf] = __builtin_amdgcn_mfma_f32_16x16x32_bf16(a, b3v[nf], gt[mt][nf], 0, 0, 0);
            }
        }
        __builtin_amdgcn_s_setprio(0);
        __builtin_amdgcn_sched_barrier(0);   // keep write block after MFMA
        if (t + 1 < 32) {
#pragma unroll
            for (int u = 0; u < 4; ++u)
                *(bf16x8*)&sh[1 - p][bbase + (rowb + u * 16) * 32 + wswz] =
                    cvt8(nb[u][0], nb[u][1]);
        }
        __syncthreads();
    }

    // ---- epilogue: silu*gate, per-wave 16x16 transpose via LDS, b16x4 store
    __bf16* trw = (__bf16*)&sh[0][0] + w * 384;    // 16 x 24 elems per wave
    int ffb = nt * 256 + w * 32;
#pragma unroll
    for (int mt = 0; mt < 4; ++mt) {
        int idx = tile * 64 + mt * 16 + ln;
#pragma unroll
        for (int nf = 0; nf < 2; ++nf) {
#pragma unroll
            for (int r = 0; r < 4; ++r) {
                float u = up[mt][nf][r], g = gt[mt][nf][r];
                float val = (u / (1.f + expf(-u))) * g;     // silu(u)*g
                trw[(q * 4 + r) * 24 + ln] = (__bf16)val;   // row=token col=ff
            }
            __asm__ volatile("s_waitcnt lgkmcnt(0)" ::: "memory");
            b16x4 v4 = *(b16x4*)&trw[ln * 24 + q * 4];
            if (idx < ne)
                *(b16x4*)(inter + (size_t)(gb + idx) * FF_ + ffb + nf * 16 + q * 4) = v4;
            __asm__ volatile("s_waitcnt lgkmcnt(0)" ::: "memory");
        }
    }
}

// ---------------------------------------------------------------------------
// K2: out[t][d] += cw * (inter[row] . w2[e][d]), same fused pipeline.
//   BM=128 tokens, BN=256 d, BK=32, K-split x4 (1024 each).
//   8 waves as 2x4, wave owns 64tok x 64d: 16 MFMA : 8 ds_read per step.
//   A (inter, bf16): 8 x global_load_lds segs, pre-swizzled source.
//   B (w2 fp32): reg-staged, per lane 2 units, swizzle on write.
// ---------------------------------------------------------------------------
__global__ __launch_bounds__(512, 4) void gemm2_kernel(
    const __bf16* __restrict__ inter, const float* __restrict__ w2f,
    const int* __restrict__ counts, const int* __restrict__ offs,
    const int* __restrict__ lists, const float* __restrict__ wlist,
    float* __restrict__ out)
{
    int bid   = blockIdx.x;
    int sx    = bid & 7;          // XCD id
    int rr    = bid >> 3;
    int tile  = rr & 15;
    int sg    = rr >> 4;
    int slice = sg * 8 + sx;      // 0..127
    int ks    = slice & 3;
    int nd    = (slice >> 2) & 3;
    int e     = slice >> 4;
    int ne    = counts[e];
    if (tile * 128 >= ne) return;
    int gb = offs[e];

    __shared__ __bf16 sh[2][12288];   // 48 KB: [A 128x32 | B 256x32]
    __shared__ int    stok[128];
    __shared__ float  swgt[128];

    int tid = threadIdx.x, lane = tid & 63, w = tid >> 6;
    int ln = lane & 15, q = lane >> 4;
    int r4 = lane >> 2, c4 = lane & 3;
    int wm = w >> 2, wn = w & 3;

    // ---- A staging: wave w stages seg w = inter rows w*16..w*16+15 ----
    const __bf16* ga;
    {
        int row = w * 16 + r4;
        int idx = tile * 128 + row; if (idx >= ne) idx = ne - 1;
        ga = inter + (size_t)(gb + idx) * FF_ + ks * 1024
                   + ((c4 ^ ((row >> 1) & 3)) * 8);
    }

    // ---- B reg staging: per lane 2 units ----
    int rowb = w * 32 + (lane >> 2);                 // 0..255 local B row
    const float* gB = w2f + ((size_t)e * D_ + nd * 256 + rowb) * FF_
                          + ks * 1024 + (lane & 3) * 8;
    int wswz = ((lane & 3) ^ ((lane >> 3) & 3)) * 8;

    int cxs = (q ^ ((ln >> 1) & 3)) * 8;
    int aoff[4], boff[4];
#pragma unroll
    for (int mt = 0; mt < 4; ++mt) aoff[mt] = (wm * 64 + mt * 16 + ln) * 32 + cxs;
#pragma unroll
    for (int nf = 0; nf < 4; ++nf)
        boff[nf] = 4096 + (wn * 64 + nf * 16 + ln) * 32 + cxs;

    f32x4 acc[4][4];
#pragma unroll
    for (int mt = 0; mt < 4; ++mt)
#pragma unroll
        for (int nf = 0; nf < 4; ++nf) acc[mt][nf] = (f32x4){0.f, 0.f, 0.f, 0.f};

    // ---- prologue: stage step 0, load token/weight table ----
    {
        float4 rb[2][2];
#pragma unroll
        for (int u = 0; u < 2; ++u) {
            const float* p = gB + (size_t)(u * 16) * FF_;
            rb[u][0] = ((const float4*)p)[0];
            rb[u][1] = ((const float4*)p)[1];
        }
        async_copy16(ga, &sh[0][w * 512]);
#pragma unroll
        for (int u = 0; u < 2; ++u)
            *(bf16x8*)&sh[0][4096 + (rowb + u * 16) * 32 + wswz] =
                cvt8(rb[u][0], rb[u][1]);
    }
    if (tid < 128) {
        int idx = tile * 128 + tid;
        int c   = idx < ne ? idx : ne - 1;
        stok[tid] = lists[e * T_ + c];
        swgt[tid] = (idx < ne) ? wlist[e * T_ + idx] : 0.f;
    }
    __syncthreads();

    // ---- K loop: 32 steps of BK=32 (this K-split's 1024) ----
    for (int t = 0; t < 32; ++t) {
        int p = t & 1;
        float4 nb[2][2];
        if (t + 1 < 32) {
#pragma unroll
            for (int u = 0; u < 2; ++u) {
                const float* pp = gB + (size_t)(u * 16) * FF_ + (t + 1) * 32;
                nb[u][0] = ((const float4*)pp)[0];
                nb[u][1] = ((const float4*)pp)[1];
            }
            async_copy16(ga + (t + 1) * 32, &sh[1 - p][w * 512]);
        }
        const __bf16* S = sh[p];
        bf16x8 b[4];
#pragma unroll
        for (int nf = 0; nf < 4; ++nf) b[nf] = *(const bf16x8*)(S + boff[nf]);
        __builtin_amdgcn_s_setprio(1);
#pragma unroll
        for (int mt = 0; mt < 4; ++mt) {
            bf16x8 a = *(const bf16x8*)(S + aoff[mt]);
#pragma unroll
            for (int nf = 0; nf < 4; ++nf)
                acc[mt][nf] = __builtin_amdgcn_mfma_f32_16x16x32_bf16(a, b[nf], acc[mt][nf], 0, 0, 0);
        }
        __builtin_amdgcn_s_setprio(0);
        __builtin_amdgcn_sched_barrier(0);   // keep write block after MFMA
        if (t + 1 < 32) {
#pragma unroll
            for (int u = 0; u < 2; ++u)
                *(bf16x8*)&sh[1 - p][4096 + (rowb + u * 16) * 32 + wswz] =
                    cvt8(nb[u][0], nb[u][1]);
        }
        __syncthreads();
    }

    // ---- epilogue: weighted atomic scatter. C/D: row=q*4+r (token), col=ln
    int dbase = nd * 256 + wn * 64;
#pragma unroll
    for (int mt = 0; mt < 4; ++mt) {
#pragma unroll
        for (int r = 0; r < 4; ++r) {
            int m = wm * 64 + mt * 16 + q * 4 + r;
            float wgt = swgt[m];
            if (wgt != 0.f) {
                int tok = stok[m];
#pragma unroll
                for (int nf = 0; nf < 4; ++nf)
                    atomicAdd(out + (size_t)tok * D_ + dbase + nf * 16 + ln,
                              wgt * acc[mt][nf][r]);
            }
        }
    }
}

extern "C" void kernel_launch(void* const* d_in, const int* in_sizes, int n_in,
                              void* d_out, int out_size, void* d_ws, size_t ws_size,
                              hipStream_t stream)
{
    const float* h  = (const float*)d_in[0];   // [1,2048,1024]
    const float* gw = (const float*)d_in[1];   // [8,1024]
    const float* w1 = (const float*)d_in[2];   // [8,4096,1024]
    const float* w3 = (const float*)d_in[3];   // [8,4096,1024]
    const float* w2 = (const float*)d_in[4];   // [8,1024,4096]

    float* out    = (float*)d_out;             // [2048*1024] then logits
    float* logits = out + (size_t)T_ * D_;     // [2048*8]

    // workspace layout (weights now read fp32 directly -> no bf16 copies)
    char*   ws     = (char*)d_ws;
    size_t  off    = 0;
    int*    counts = (int*)(ws + off); off += 128;
    int*    offs   = (int*)(ws + off); off += 128;
    int*    lists  = (int*)(ws + off); off += (size_t)E_ * T_ * 4;
    float*  wlist  = (float*)(ws + off); off += (size_t)E_ * T_ * 4;
    __bf16* hbf    = (__bf16*)(ws + off); off += (size_t)T_ * D_ * 2;      // 4 MB
    __bf16* inter  = (__bf16*)(ws + off); off += (size_t)T_ * 2 * FF_ * 2; // 32 MB
    (void)ws_size;

    hipMemsetAsync(counts, 0, 256, stream);
    hipMemsetAsync(out, 0, (size_t)T_ * D_ * sizeof(float), stream);

    router_kernel<<<T_ / 4, 256, 0, stream>>>(h, gw, hbf, logits, counts, lists, wlist);
    prefix_kernel<<<1, 64, 0, stream>>>(counts, offs);

    gemm1_kernel<<<32 * 128, 512, 0, stream>>>(hbf, w1, w3, counts, offs, lists, inter);
    gemm2_kernel<<<16 * 128, 512, 0, stream>>>(inter, w2, counts, offs, lists, wlist, out);
}